// Round 24
// baseline (84.019 us; speedup 1.0000x reference)
//
#include <hip/hip_runtime.h>

// Problem constants
#define BDIM   16
#define PDIM   12
#define TDIM   4096
#define WINW   41
#define PADW   20
#define DDIM   492      // P*WIN
#define KCODES 1024

// fp8 16x16x32 MFMA, PAIRED-K layout (R12-verified, absmax 0).
// R23: 1024-thr/16-wave blocks -> 4 waves/SIMD (occ 41%) improved 86->77
// even WITH spill. The spill came from the rotating prefetch (b0/b1/nx = 12
// regs live across the MFMA burst) -- and R22 proved rotation is NULL anyway.
// R24 = R23 minus rotation: just-in-time paired b128 reads. Live ~52 <= 64
// -> zero in-loop spill. At 4 waves/SIMD the ~120cyc read latency is covered
// by the other 3 waves' MFMAs -- no software pipelining needed.
#define KSTEPS   16                  // K-steps of 32 -> 512
#define KPAIRS   8                   // paired K-steps (b128 reads)
#define TILE_BYTES (KPAIRS * 64 * 16)   // 8 KiB per 16-code tile

#define WAVES    16                  // 1024-thread blocks
#define ROWS_WAVE 16
#define BMROWS   (WAVES * ROWS_WAVE) // 256 rows per block
#define MROWS    (BDIM * TDIM)       // 65536
#define NBLK     (MROWS / BMROWS)    // 256 = 1 block/CU, single round
#define NQ       4                   // codebook quarters
#define QTILES   16                  // 16-code tiles per quarter
#define QBYTES   (QTILES * TILE_BYTES)   // 128 KiB

typedef __attribute__((ext_vector_type(4))) float f32x4;
typedef __attribute__((ext_vector_type(2))) long  long2v;

// two f32 pairs -> 4 e4m3 bytes (RNE, saturating) via v_cvt_pk_fp8_f32
__device__ __forceinline__ unsigned int pack4_fp8(float a, float b, float c, float d) {
    int v = 0;
    v = __builtin_amdgcn_cvt_pk_fp8_f32(a, b, v, false);  // bytes 0,1
    v = __builtin_amdgcn_cvt_pk_fp8_f32(c, d, v, true);   // bytes 2,3
    return (unsigned int)v;
}

__device__ __forceinline__ long pack8_fp8(const float* v) {
    unsigned int lo = pack4_fp8(v[0], v[1], v[2], v[3]);
    unsigned int hi = pack4_fp8(v[4], v[5], v[6], v[7]);
    return (long)(((unsigned long long)hi << 32) | lo);
}

// Pre-format codebook into fp8 B-fragments for mfma_f32_16x16x32_fp8_fp8,
// PAIRED-K layout (identical to R12, which passed):
//   entry e = (nt*KPAIRS + kp)*64 + lane holds 16 bytes:
//     long0: B[k][n], k = kp*64 +      hi*8 + j   (ks = 2kp)
//     long1: B[k][n], k = kp*64 + 32 + hi*8 + j   (ks = 2kp+1)
//   n = nt*16 + (lane&15), hi = lane>>4.
__global__ __launch_bounds__(256) void prep_bfrag_k(const float* __restrict__ cb,
                                                    long2v* __restrict__ bfrag) {
    int e    = blockIdx.x * 256 + threadIdx.x;   // 0..32767
    int lane = e & 63;
    int kp   = (e >> 6) & (KPAIRS - 1);
    int nt   = e >> 9;
    int n    = nt * 16 + (lane & 15);
    int hi   = lane >> 4;
    float v0[8], v1[8];
#pragma unroll
    for (int j = 0; j < 8; ++j) {
        int k0 = kp * 64 + hi * 8 + j;
        int k1 = k0 + 32;
        v0[j] = (k0 < DDIM) ? cb[n * DDIM + k0] : 0.f;
        v1[j] = (k1 < DDIM) ? cb[n * DDIM + k1] : 0.f;
    }
    long2v out;
    out[0] = pack8_fp8(v0);
    out[1] = pack8_fp8(v1);
    bfrag[e] = out;
}

// Exact fp32 code norms.
__global__ __launch_bounds__(64) void prep_cnorm_k(const float* __restrict__ cb,
                                                   float* __restrict__ cnorm) {
    int n = blockIdx.x;
    int lane = threadIdx.x;
    float s = 0.f;
    for (int d = lane; d < DDIM; d += 64) { float c = cb[n * DDIM + d]; s += c * c; }
#pragma unroll
    for (int m = 1; m < 64; m <<= 1) s += __shfl_xor(s, m, 64);
    if (lane == 0) cnorm[n] = s;
}

// Exact sum of ||f||^2 over all rows via window multiplicity:
// mult(tt) = 41 - max(0,20-tt) - max(0,tt-4075).
__global__ __launch_bounds__(256) void xsq_k(const float* __restrict__ x,
                                             float* __restrict__ xsq_part) {
    float s = 0.f;
    for (int i = blockIdx.x * 256 + threadIdx.x; i < BDIM * PDIM * TDIM; i += 256 * 256) {
        int tt = i & (TDIM - 1);
        int mult = WINW - max(0, PADW - tt) - max(0, tt - (TDIM - 1 - PADW));
        float v = x[i];
        s += (float)mult * v * v;
    }
#pragma unroll
    for (int m = 1; m < 64; m <<= 1) s += __shfl_xor(s, m, 64);
    __shared__ float sm[4];
    if ((threadIdx.x & 63) == 0) sm[threadIdx.x >> 6] = s;
    __syncthreads();
    if (threadIdx.x == 0) xsq_part[blockIdx.x] = sm[0] + sm[1] + sm[2] + sm[3];
}

// Stage one 128 KiB quarter into LDS: 1024 thr x 16 B = 16 KiB per round,
// 8 rounds -> 8 global_load_lds per thread.
__device__ __forceinline__ void stage_quarter(const unsigned char* __restrict__ gq,
                                              unsigned char* smem, int wave, int lane) {
#pragma unroll
    for (int i = 0; i < 8; ++i) {
        int off = i * 16384 + wave * 1024;
        __builtin_amdgcn_global_load_lds(
            (const __attribute__((address_space(1))) unsigned int*)(gq + off + lane * 16),
            (__attribute__((address_space(3))) unsigned int*)(smem + off),
            16, 0, 0);
    }
}

// Main sweep: 256 blocks (1/CU) x 16 waves x 16 rows, single round.
// Prologue: stage quarter 0 + sb table + A-build (once) + one sync. Then 4x
// { barrier-free sweep (16 tiles x 8 just-in-time paired b128 reads x 16
// MFMAs, zero sync inside); sync; restage; sync }. Live ~52 regs <= the
// 64-VGPR pin of 1024-thr blocks -> zero in-loop spill.
__global__ __launch_bounds__(1024)
void vq_main_k(const float* __restrict__ x,
               const unsigned char* __restrict__ bfrag,
               const float* __restrict__ cnorm,
               float* __restrict__ bpart) {
    __shared__ __align__(16) unsigned char smem[QBYTES];   // 128 KiB
    __shared__ float sb_lds[KCODES];                       // 4 KiB
    __shared__ float gsum[4 * WAVES];

    const int lane = threadIdx.x & 63;
    const int wave = threadIdx.x >> 6;
    const int col  = lane & 15;     // B/D column within 16-code tile
    const int hi   = lane >> 4;
    const int rowbase = blockIdx.x * BMROWS + wave * ROWS_WAVE;

    // Stage quarter 0; latency covered by sb-table + A-build below.
    stage_quarter(bfrag, smem, wave, lane);

    // Full bias table: sb_lds[n] = -0.5*||c_n||^2
    for (int i = threadIdx.x; i < KCODES; i += 1024)
        sb_lds[i] = -0.5f * cnorm[i];

    // ---- Build fp8 A-slab ONCE: row = rowbase + col, k = ks*32 + hi*8+j ----
    long afr[KSTEPS];
    {
        int row = rowbase + col;
        int b = row >> 12;
        int t = row & (TDIM - 1);
        const float* xb = x + (size_t)b * (PDIM * TDIM);
#pragma unroll
        for (int ks = 0; ks < KSTEPS; ++ks) {
            float v[8];
#pragma unroll
            for (int j = 0; j < 8; ++j) {
                int d = ks * 32 + hi * 8 + j;
                float f = 0.f;
                if (d < DDIM) {
                    int p  = d / WINW;
                    int w  = d - p * WINW;
                    int tt = t + w - PADW;
                    if (tt >= 0 && tt < TDIM) f = xb[p * TDIM + tt];
                }
                v[j] = f;
            }
            afr[ks] = pack8_fp8(v);
        }
    }

    float bs[4];
#pragma unroll
    for (int r = 0; r < 4; ++r) bs[r] = -3.0e38f;

    // Entry drain: quarter 0 resident; sb_lds visible.
    __syncthreads();

    for (int q = 0; q < NQ; ++q) {
        // ---- Barrier-free sweep of the resident quarter ----
        for (int tl = 0; tl < QTILES; ++tl) {
            const long2v* bp = (const long2v*)(smem + tl * TILE_BYTES) + lane;
            f32x4 acc = {0.f, 0.f, 0.f, 0.f};
#pragma unroll
            for (int kp = 0; kp < KPAIRS; ++kp) {
                long2v bq = bp[kp * 64];   // ds_read_b128: ks=2kp, 2kp+1
                acc = __builtin_amdgcn_mfma_f32_16x16x32_fp8_fp8(afr[2 * kp],     bq[0], acc, 0, 0, 0);
                acc = __builtin_amdgcn_mfma_f32_16x16x32_fp8_fp8(afr[2 * kp + 1], bq[1], acc, 0, 0, 0);
            }
            const float sb = sb_lds[q * (KCODES / NQ) + tl * 16 + col];
#pragma unroll
            for (int r = 0; r < 4; ++r)          // D: col=lane&15, row=hi*4+r
                bs[r] = fmaxf(bs[r], acc[r] + sb);
        }
        // ---- Restage next quarter (2 barriers per transition) ----
        if (q + 1 < NQ) {
            __syncthreads();   // all waves done reading smem
            stage_quarter(bfrag + (size_t)(q + 1) * QBYTES, smem, wave, lane);
            __syncthreads();   // drains vmcnt(0): next quarter resident
        }
    }

    // ---- Per-row max across the 16 col-lanes (masks<16 preserve hi) ----
#pragma unroll
    for (int m = 1; m < 16; m <<= 1)
#pragma unroll
        for (int r = 0; r < 4; ++r)
            bs[r] = fmaxf(bs[r], __shfl_xor(bs[r], m, 64));

    // Lane col==0 of each 16-lane group owns rows {hi*4 + r} of the slab.
    if (col == 0) {
        float s = 0.f;
#pragma unroll
        for (int r = 0; r < 4; ++r) s += bs[r];
        gsum[wave * 4 + hi] = s;
    }
    __syncthreads();
    if (threadIdx.x == 0) {
        float tot = 0.f;
#pragma unroll
        for (int i = 0; i < 4 * WAVES; ++i) tot += gsum[i];
        bpart[blockIdx.x] = tot;
    }
}

// loss = 0.25 * (Sxx - 2*sum_blocks bpart) / (65536*492)
__global__ __launch_bounds__(256) void finalize_k(const float* __restrict__ bpart,
                                                  const float* __restrict__ xsq_part,
                                                  float* __restrict__ out) {
    __shared__ double sm[256];
    int tid = threadIdx.x;
    sm[tid] = (double)bpart[tid];
    __syncthreads();
    for (int st = 128; st > 0; st >>= 1) {
        if (tid < st) sm[tid] += sm[tid + st];
        __syncthreads();
    }
    double S1 = sm[0];
    __syncthreads();
    sm[tid] = (double)xsq_part[tid];
    __syncthreads();
    for (int st = 128; st > 0; st >>= 1) {
        if (tid < st) sm[tid] += sm[tid + st];
        __syncthreads();
    }
    if (tid == 0)
        out[0] = (float)(0.25 * (sm[0] - 2.0 * S1) / ((double)MROWS * (double)DDIM));
}

extern "C" void kernel_launch(void* const* d_in, const int* in_sizes, int n_in,
                              void* d_out, int out_size, void* d_ws, size_t ws_size,
                              hipStream_t stream) {
    const float* x  = (const float*)d_in[0];   // (16,12,4096) f32
    const float* cb = (const float*)d_in[1];   // (1024,492) f32
    float* out = (float*)d_out;

    // workspace layout (~524 KiB)
    char* ws = (char*)d_ws;
    long2v* bfrag   = (long2v*)ws;                                  // 512 KiB
    float* cnorm    = (float*)(ws + (512u << 10));                  // 4 KiB
    float* xsq_part = (float*)(ws + (512u << 10) + 4096);           // 1 KiB
    float* bpart    = (float*)(ws + (512u << 10) + 8192);           // 1 KiB

    prep_bfrag_k<<<128, 256, 0, stream>>>(cb, bfrag);
    prep_cnorm_k<<<KCODES, 64, 0, stream>>>(cb, cnorm);
    xsq_k<<<256, 256, 0, stream>>>(x, xsq_part);
    vq_main_k<<<NBLK, 1024, 0, stream>>>(x, (const unsigned char*)bfrag, cnorm, bpart);
    finalize_k<<<1, 256, 0, stream>>>(bpart, xsq_part, out);
}

// Round 25
// 83.441 us; speedup vs baseline: 1.0069x; 1.0069x over previous
//
#include <hip/hip_runtime.h>

// Problem constants
#define BDIM   16
#define PDIM   12
#define TDIM   4096
#define WINW   41
#define PADW   20
#define DDIM   492      // P*WIN
#define KCODES 1024

// fp8 16x16x32 MFMA, PAIRED-K layout (R12-verified, absmax 0).
// R23/R24: 1024-thr/16-wave blocks -> 4 waves/SIMD (occ 41%) is the right
// axis (steady 86->78) but the A-build prologue spilled ~30 regs (WRITE
// 37.5MB) because the unrolled build (v[8] + temps) peaks >> 64. R25:
// pressure-bounded A-build -- incremental cvt_pk (2 floats at a time, no
// v[8]) + sched_barrier(0) fence after each ks so the scheduler cannot
// interleave iterations. Peak ~= afr(32)+12 <= 64 -> no spill.
#define KSTEPS   16                  // K-steps of 32 -> 512
#define KPAIRS   8                   // paired K-steps (b128 reads)
#define TILE_BYTES (KPAIRS * 64 * 16)   // 8 KiB per 16-code tile

#define WAVES    16                  // 1024-thread blocks
#define ROWS_WAVE 16
#define BMROWS   (WAVES * ROWS_WAVE) // 256 rows per block
#define MROWS    (BDIM * TDIM)       // 65536
#define NBLK     (MROWS / BMROWS)    // 256 = 1 block/CU, single round
#define NQ       4                   // codebook quarters
#define QTILES   16                  // 16-code tiles per quarter
#define QBYTES   (QTILES * TILE_BYTES)   // 128 KiB

typedef __attribute__((ext_vector_type(4))) float f32x4;
typedef __attribute__((ext_vector_type(2))) long  long2v;

// two f32 pairs -> 4 e4m3 bytes (RNE, saturating) via v_cvt_pk_fp8_f32
__device__ __forceinline__ unsigned int pack4_fp8(float a, float b, float c, float d) {
    int v = 0;
    v = __builtin_amdgcn_cvt_pk_fp8_f32(a, b, v, false);  // bytes 0,1
    v = __builtin_amdgcn_cvt_pk_fp8_f32(c, d, v, true);   // bytes 2,3
    return (unsigned int)v;
}

__device__ __forceinline__ long pack8_fp8(const float* v) {
    unsigned int lo = pack4_fp8(v[0], v[1], v[2], v[3]);
    unsigned int hi = pack4_fp8(v[4], v[5], v[6], v[7]);
    return (long)(((unsigned long long)hi << 32) | lo);
}

// Pre-format codebook into fp8 B-fragments for mfma_f32_16x16x32_fp8_fp8,
// PAIRED-K layout (identical to R12, which passed):
//   entry e = (nt*KPAIRS + kp)*64 + lane holds 16 bytes:
//     long0: B[k][n], k = kp*64 +      hi*8 + j   (ks = 2kp)
//     long1: B[k][n], k = kp*64 + 32 + hi*8 + j   (ks = 2kp+1)
//   n = nt*16 + (lane&15), hi = lane>>4.
__global__ __launch_bounds__(256) void prep_bfrag_k(const float* __restrict__ cb,
                                                    long2v* __restrict__ bfrag) {
    int e    = blockIdx.x * 256 + threadIdx.x;   // 0..32767
    int lane = e & 63;
    int kp   = (e >> 6) & (KPAIRS - 1);
    int nt   = e >> 9;
    int n    = nt * 16 + (lane & 15);
    int hi   = lane >> 4;
    float v0[8], v1[8];
#pragma unroll
    for (int j = 0; j < 8; ++j) {
        int k0 = kp * 64 + hi * 8 + j;
        int k1 = k0 + 32;
        v0[j] = (k0 < DDIM) ? cb[n * DDIM + k0] : 0.f;
        v1[j] = (k1 < DDIM) ? cb[n * DDIM + k1] : 0.f;
    }
    long2v out;
    out[0] = pack8_fp8(v0);
    out[1] = pack8_fp8(v1);
    bfrag[e] = out;
}

// Exact fp32 code norms.
__global__ __launch_bounds__(64) void prep_cnorm_k(const float* __restrict__ cb,
                                                   float* __restrict__ cnorm) {
    int n = blockIdx.x;
    int lane = threadIdx.x;
    float s = 0.f;
    for (int d = lane; d < DDIM; d += 64) { float c = cb[n * DDIM + d]; s += c * c; }
#pragma unroll
    for (int m = 1; m < 64; m <<= 1) s += __shfl_xor(s, m, 64);
    if (lane == 0) cnorm[n] = s;
}

// Exact sum of ||f||^2 over all rows via window multiplicity:
// mult(tt) = 41 - max(0,20-tt) - max(0,tt-4075).
__global__ __launch_bounds__(256) void xsq_k(const float* __restrict__ x,
                                             float* __restrict__ xsq_part) {
    float s = 0.f;
    for (int i = blockIdx.x * 256 + threadIdx.x; i < BDIM * PDIM * TDIM; i += 256 * 256) {
        int tt = i & (TDIM - 1);
        int mult = WINW - max(0, PADW - tt) - max(0, tt - (TDIM - 1 - PADW));
        float v = x[i];
        s += (float)mult * v * v;
    }
#pragma unroll
    for (int m = 1; m < 64; m <<= 1) s += __shfl_xor(s, m, 64);
    __shared__ float sm[4];
    if ((threadIdx.x & 63) == 0) sm[threadIdx.x >> 6] = s;
    __syncthreads();
    if (threadIdx.x == 0) xsq_part[blockIdx.x] = sm[0] + sm[1] + sm[2] + sm[3];
}

// Stage one 128 KiB quarter into LDS: 1024 thr x 16 B = 16 KiB per round,
// 8 rounds -> 8 global_load_lds per thread.
__device__ __forceinline__ void stage_quarter(const unsigned char* __restrict__ gq,
                                              unsigned char* smem, int wave, int lane) {
#pragma unroll
    for (int i = 0; i < 8; ++i) {
        int off = i * 16384 + wave * 1024;
        __builtin_amdgcn_global_load_lds(
            (const __attribute__((address_space(1))) unsigned int*)(gq + off + lane * 16),
            (__attribute__((address_space(3))) unsigned int*)(smem + off),
            16, 0, 0);
    }
}

// windowed-x fetch: element d of row with time-index t
__device__ __forceinline__ float fetchx(const float* __restrict__ xb, int t, int d) {
    if (d >= DDIM) return 0.f;
    int p  = d / WINW;
    int w  = d - p * WINW;
    int tt = t + w - PADW;
    return (tt >= 0 && tt < TDIM) ? xb[p * TDIM + tt] : 0.f;
}

// Main sweep: 256 blocks (1/CU) x 16 waves x 16 rows, single round.
// Prologue: stage quarter 0 + sb table + pressure-bounded A-build + one
// sync. Then 4x { barrier-free sweep (16 tiles x 8 paired b128 reads x 16
// MFMAs, zero sync inside); sync; restage; sync }. Live ~50 <= 64 cap.
__global__ __launch_bounds__(1024)
void vq_main_k(const float* __restrict__ x,
               const unsigned char* __restrict__ bfrag,
               const float* __restrict__ cnorm,
               float* __restrict__ bpart) {
    __shared__ __align__(16) unsigned char smem[QBYTES];   // 128 KiB
    __shared__ float sb_lds[KCODES];                       // 4 KiB
    __shared__ float gsum[4 * WAVES];

    const int lane = threadIdx.x & 63;
    const int wave = threadIdx.x >> 6;
    const int col  = lane & 15;     // B/D column within 16-code tile
    const int hi   = lane >> 4;
    const int rowbase = blockIdx.x * BMROWS + wave * ROWS_WAVE;

    // Stage quarter 0; latency covered by sb-table + A-build below.
    stage_quarter(bfrag, smem, wave, lane);

    // Full bias table: sb_lds[n] = -0.5*||c_n||^2
    for (int i = threadIdx.x; i < KCODES; i += 1024)
        sb_lds[i] = -0.5f * cnorm[i];

    // ---- Pressure-bounded fp8 A-build: row = rowbase + col,
    //      k = ks*32 + hi*8 + j. Incremental cvt_pk (2 floats live) and a
    //      sched_barrier(0) fence per ks so iterations cannot interleave
    //      (R24's spill source). ----
    long afr[KSTEPS];
    {
        int row = rowbase + col;
        int t = row & (TDIM - 1);
        const float* xb = x + (size_t)(row >> 12) * (PDIM * TDIM);
#pragma unroll
        for (int ks = 0; ks < KSTEPS; ++ks) {
            const int dbase = ks * 32 + hi * 8;
            unsigned int lo = 0, hw = 0;
            {
                float f0 = fetchx(xb, t, dbase + 0);
                float f1 = fetchx(xb, t, dbase + 1);
                lo = (unsigned int)__builtin_amdgcn_cvt_pk_fp8_f32(f0, f1, (int)lo, false);
                f0 = fetchx(xb, t, dbase + 2);
                f1 = fetchx(xb, t, dbase + 3);
                lo = (unsigned int)__builtin_amdgcn_cvt_pk_fp8_f32(f0, f1, (int)lo, true);
                f0 = fetchx(xb, t, dbase + 4);
                f1 = fetchx(xb, t, dbase + 5);
                hw = (unsigned int)__builtin_amdgcn_cvt_pk_fp8_f32(f0, f1, (int)hw, false);
                f0 = fetchx(xb, t, dbase + 6);
                f1 = fetchx(xb, t, dbase + 7);
                hw = (unsigned int)__builtin_amdgcn_cvt_pk_fp8_f32(f0, f1, (int)hw, true);
            }
            afr[ks] = (long)(((unsigned long long)hw << 32) | (unsigned long long)lo);
            __builtin_amdgcn_sched_barrier(0);   // fence: bound prologue pressure
        }
    }

    float bs[4];
#pragma unroll
    for (int r = 0; r < 4; ++r) bs[r] = -3.0e38f;

    // Entry drain: quarter 0 resident; sb_lds visible.
    __syncthreads();

    for (int q = 0; q < NQ; ++q) {
        // ---- Barrier-free sweep of the resident quarter ----
        for (int tl = 0; tl < QTILES; ++tl) {
            const long2v* bp = (const long2v*)(smem + tl * TILE_BYTES) + lane;
            f32x4 acc = {0.f, 0.f, 0.f, 0.f};
#pragma unroll
            for (int kp = 0; kp < KPAIRS; ++kp) {
                long2v bq = bp[kp * 64];   // ds_read_b128: ks=2kp, 2kp+1
                acc = __builtin_amdgcn_mfma_f32_16x16x32_fp8_fp8(afr[2 * kp],     bq[0], acc, 0, 0, 0);
                acc = __builtin_amdgcn_mfma_f32_16x16x32_fp8_fp8(afr[2 * kp + 1], bq[1], acc, 0, 0, 0);
            }
            const float sb = sb_lds[q * (KCODES / NQ) + tl * 16 + col];
#pragma unroll
            for (int r = 0; r < 4; ++r)          // D: col=lane&15, row=hi*4+r
                bs[r] = fmaxf(bs[r], acc[r] + sb);
        }
        // ---- Restage next quarter (2 barriers per transition) ----
        if (q + 1 < NQ) {
            __syncthreads();   // all waves done reading smem
            stage_quarter(bfrag + (size_t)(q + 1) * QBYTES, smem, wave, lane);
            __syncthreads();   // drains vmcnt(0): next quarter resident
        }
    }

    // ---- Per-row max across the 16 col-lanes (masks<16 preserve hi) ----
#pragma unroll
    for (int m = 1; m < 16; m <<= 1)
#pragma unroll
        for (int r = 0; r < 4; ++r)
            bs[r] = fmaxf(bs[r], __shfl_xor(bs[r], m, 64));

    // Lane col==0 of each 16-lane group owns rows {hi*4 + r} of the slab.
    if (col == 0) {
        float s = 0.f;
#pragma unroll
        for (int r = 0; r < 4; ++r) s += bs[r];
        gsum[wave * 4 + hi] = s;
    }
    __syncthreads();
    if (threadIdx.x == 0) {
        float tot = 0.f;
#pragma unroll
        for (int i = 0; i < 4 * WAVES; ++i) tot += gsum[i];
        bpart[blockIdx.x] = tot;
    }
}

// loss = 0.25 * (Sxx - 2*sum_blocks bpart) / (65536*492)
__global__ __launch_bounds__(256) void finalize_k(const float* __restrict__ bpart,
                                                  const float* __restrict__ xsq_part,
                                                  float* __restrict__ out) {
    __shared__ double sm[256];
    int tid = threadIdx.x;
    sm[tid] = (double)bpart[tid];
    __syncthreads();
    for (int st = 128; st > 0; st >>= 1) {
        if (tid < st) sm[tid] += sm[tid + st];
        __syncthreads();
    }
    double S1 = sm[0];
    __syncthreads();
    sm[tid] = (double)xsq_part[tid];
    __syncthreads();
    for (int st = 128; st > 0; st >>= 1) {
        if (tid < st) sm[tid] += sm[tid + st];
        __syncthreads();
    }
    if (tid == 0)
        out[0] = (float)(0.25 * (sm[0] - 2.0 * S1) / ((double)MROWS * (double)DDIM));
}

extern "C" void kernel_launch(void* const* d_in, const int* in_sizes, int n_in,
                              void* d_out, int out_size, void* d_ws, size_t ws_size,
                              hipStream_t stream) {
    const float* x  = (const float*)d_in[0];   // (16,12,4096) f32
    const float* cb = (const float*)d_in[1];   // (1024,492) f32
    float* out = (float*)d_out;

    // workspace layout (~524 KiB)
    char* ws = (char*)d_ws;
    long2v* bfrag   = (long2v*)ws;                                  // 512 KiB
    float* cnorm    = (float*)(ws + (512u << 10));                  // 4 KiB
    float* xsq_part = (float*)(ws + (512u << 10) + 4096);           // 1 KiB
    float* bpart    = (float*)(ws + (512u << 10) + 8192);           // 1 KiB

    prep_bfrag_k<<<128, 256, 0, stream>>>(cb, bfrag);
    prep_cnorm_k<<<KCODES, 64, 0, stream>>>(cb, cnorm);
    xsq_k<<<256, 256, 0, stream>>>(x, xsq_part);
    vq_main_k<<<NBLK, 1024, 0, stream>>>(x, (const unsigned char*)bfrag, cnorm, bpart);
    finalize_k<<<1, 256, 0, stream>>>(bpart, xsq_part, out);
}

// Round 26
// 61.052 us; speedup vs baseline: 1.3762x; 1.3667x over previous
//
#include <hip/hip_runtime.h>

// Problem constants
#define BDIM   16
#define PDIM   12
#define TDIM   4096
#define WINW   41
#define PADW   20
#define DDIM   492      // P*WIN
#define KCODES 1024

// MX-scaled fp8 MFMA: mfma_scale_f32_16x16x128_f8f6f4 with all block scales
// = 1.0 (e8m0 127) == pure fp8 GEMM at 2x the non-scaled rate. K=128/instr
// -> 4 MFMAs per 16-code tile (vs 16 at K=32). R20-R25 invariant: per-wave
// serial overhead ~170cyc PER MFMA INSTRUCTION (independent of waves/chains/
// prefetch) -> 4x fewer instructions is the remaining lever. LDS bytes and
// read count per tile unchanged (8 x b128).
#define KCHUNK   4                   // K=128 chunks covering 512
#define TILE_BYTES (KCHUNK * 2 * 64 * 16)   // 8 KiB per 16-code tile

#define WAVES    16                  // 1024-thread blocks (4 waves/SIMD)
#define ROWS_WAVE 16
#define BMROWS   (WAVES * ROWS_WAVE) // 256 rows per block
#define MROWS    (BDIM * TDIM)       // 65536
#define NBLK     (MROWS / BMROWS)    // 256 = 1 block/CU, single round
#define NQ       4                   // codebook quarters
#define QTILES   16                  // 16-code tiles per quarter
#define QBYTES   (QTILES * TILE_BYTES)   // 128 KiB

#define SCALE1   0x7F7F7F7F          // 4x e8m0(127) = 1.0 per 32-elem block

typedef __attribute__((ext_vector_type(4))) float f32x4;
typedef __attribute__((ext_vector_type(2))) long  long2v;
typedef __attribute__((ext_vector_type(4))) int   int4v;
typedef __attribute__((ext_vector_type(8))) int   int8v;

// two f32 pairs -> 4 e4m3 bytes (RNE, saturating) via v_cvt_pk_fp8_f32
__device__ __forceinline__ unsigned int pack4_fp8(float a, float b, float c, float d) {
    int v = 0;
    v = __builtin_amdgcn_cvt_pk_fp8_f32(a, b, v, false);  // bytes 0,1
    v = __builtin_amdgcn_cvt_pk_fp8_f32(c, d, v, true);   // bytes 2,3
    return (unsigned int)v;
}

__device__ __forceinline__ long pack8_fp8(const float* v) {
    unsigned int lo = pack4_fp8(v[0], v[1], v[2], v[3]);
    unsigned int hi = pack4_fp8(v[4], v[5], v[6], v[7]);
    return (long)(((unsigned long long)hi << 32) | lo);
}

// Pre-format codebook into fp8 B-fragments for mfma_scale_f32_16x16x128.
// Entry e = ((nt*KCHUNK + kc)*2 + half)*64 + lane holds 16 bytes:
//   B[k][n], n = nt*16 + (lane&15), k = kc*128 + (lane>>4)*32 + half*16 + jj
//   (jj = 0..15). Within a tile: offset = kc*2048 + half*1024 + lane*16 ->
//   both b128 reads per MFMA are 16B-stride (bank-conflict-free).
__global__ __launch_bounds__(256) void prep_bfrag_k(const float* __restrict__ cb,
                                                    long2v* __restrict__ bfrag) {
    int e    = blockIdx.x * 256 + threadIdx.x;   // 0..32767
    int lane = e & 63;
    int half = (e >> 6) & 1;
    int kc   = (e >> 7) & (KCHUNK - 1);
    int nt   = e >> 9;
    int n    = nt * 16 + (lane & 15);
    int k0   = kc * 128 + (lane >> 4) * 32 + half * 16;
    float v0[8], v1[8];
#pragma unroll
    for (int j = 0; j < 8; ++j) {
        int ka = k0 + j;
        int kb = k0 + 8 + j;
        v0[j] = (ka < DDIM) ? cb[n * DDIM + ka] : 0.f;
        v1[j] = (kb < DDIM) ? cb[n * DDIM + kb] : 0.f;
    }
    long2v out;
    out[0] = pack8_fp8(v0);
    out[1] = pack8_fp8(v1);
    bfrag[e] = out;
}

// Exact fp32 code norms.
__global__ __launch_bounds__(64) void prep_cnorm_k(const float* __restrict__ cb,
                                                   float* __restrict__ cnorm) {
    int n = blockIdx.x;
    int lane = threadIdx.x;
    float s = 0.f;
    for (int d = lane; d < DDIM; d += 64) { float c = cb[n * DDIM + d]; s += c * c; }
#pragma unroll
    for (int m = 1; m < 64; m <<= 1) s += __shfl_xor(s, m, 64);
    if (lane == 0) cnorm[n] = s;
}

// Exact sum of ||f||^2 over all rows via window multiplicity:
// mult(tt) = 41 - max(0,20-tt) - max(0,tt-4075).
__global__ __launch_bounds__(256) void xsq_k(const float* __restrict__ x,
                                             float* __restrict__ xsq_part) {
    float s = 0.f;
    for (int i = blockIdx.x * 256 + threadIdx.x; i < BDIM * PDIM * TDIM; i += 256 * 256) {
        int tt = i & (TDIM - 1);
        int mult = WINW - max(0, PADW - tt) - max(0, tt - (TDIM - 1 - PADW));
        float v = x[i];
        s += (float)mult * v * v;
    }
#pragma unroll
    for (int m = 1; m < 64; m <<= 1) s += __shfl_xor(s, m, 64);
    __shared__ float sm[4];
    if ((threadIdx.x & 63) == 0) sm[threadIdx.x >> 6] = s;
    __syncthreads();
    if (threadIdx.x == 0) xsq_part[blockIdx.x] = sm[0] + sm[1] + sm[2] + sm[3];
}

// Stage one 128 KiB quarter into LDS: 1024 thr x 16 B = 16 KiB per round,
// 8 rounds -> 8 global_load_lds per thread.
__device__ __forceinline__ void stage_quarter(const unsigned char* __restrict__ gq,
                                              unsigned char* smem, int wave, int lane) {
#pragma unroll
    for (int i = 0; i < 8; ++i) {
        int off = i * 16384 + wave * 1024;
        __builtin_amdgcn_global_load_lds(
            (const __attribute__((address_space(1))) unsigned int*)(gq + off + lane * 16),
            (__attribute__((address_space(3))) unsigned int*)(smem + off),
            16, 0, 0);
    }
}

// windowed-x fetch: element d of row with time-index t
__device__ __forceinline__ float fetchx(const float* __restrict__ xb, int t, int d) {
    if (d >= DDIM) return 0.f;
    int p  = d / WINW;
    int w  = d - p * WINW;
    int tt = t + w - PADW;
    return (tt >= 0 && tt < TDIM) ? xb[p * TDIM + tt] : 0.f;
}

// Main sweep: 256 blocks (1/CU) x 16 waves x 16 rows, single round.
// Prologue: stage quarter 0 + sb table + A-build + one sync. Then 4x
// { barrier-free sweep (16 tiles x 4 MX-MFMAs x 8 b128 reads, zero sync
// inside); sync; restage; sync }. All scales 1.0 -> plain fp8 GEMM at 2x
// rate with 4x fewer MFMA instructions.
__global__ __launch_bounds__(1024)
void vq_main_k(const float* __restrict__ x,
               const unsigned char* __restrict__ bfrag,
               const float* __restrict__ cnorm,
               float* __restrict__ bpart) {
    __shared__ __align__(16) unsigned char smem[QBYTES];   // 128 KiB
    __shared__ float sb_lds[KCODES];                       // 4 KiB
    __shared__ float gsum[4 * WAVES];

    const int lane = threadIdx.x & 63;
    const int wave = threadIdx.x >> 6;
    const int col  = lane & 15;     // B/D column within 16-code tile
    const int hi   = lane >> 4;
    const int rowbase = blockIdx.x * BMROWS + wave * ROWS_WAVE;

    // Stage quarter 0; latency covered by sb-table + A-build below.
    stage_quarter(bfrag, smem, wave, lane);

    // Full bias table: sb_lds[n] = -0.5*||c_n||^2
    for (int i = threadIdx.x; i < KCODES; i += 1024)
        sb_lds[i] = -0.5f * cnorm[i];

    // ---- fp8 A-build: row = rowbase + col, k = kc*128 + hi*32 + 4m + b ----
    int8v afr[KCHUNK];
    {
        int row = rowbase + col;
        int t = row & (TDIM - 1);
        const float* xb = x + (size_t)(row >> 12) * (PDIM * TDIM);
#pragma unroll
        for (int kc = 0; kc < KCHUNK; ++kc) {
#pragma unroll
            for (int m = 0; m < 8; ++m) {
                int d = kc * 128 + hi * 32 + m * 4;
                float f0 = fetchx(xb, t, d + 0);
                float f1 = fetchx(xb, t, d + 1);
                float f2 = fetchx(xb, t, d + 2);
                float f3 = fetchx(xb, t, d + 3);
                afr[kc][m] = (int)pack4_fp8(f0, f1, f2, f3);
            }
            __builtin_amdgcn_sched_barrier(0);   // bound prologue pressure
        }
    }

    float bs[4];
#pragma unroll
    for (int r = 0; r < 4; ++r) bs[r] = -3.0e38f;

    // Entry drain: quarter 0 resident; sb_lds visible.
    __syncthreads();

    for (int q = 0; q < NQ; ++q) {
        // ---- Barrier-free sweep of the resident quarter ----
        for (int tl = 0; tl < QTILES; ++tl) {
            const unsigned char* tb = smem + tl * TILE_BYTES;
            f32x4 acc = {0.f, 0.f, 0.f, 0.f};
#pragma unroll
            for (int kc = 0; kc < KCHUNK; ++kc) {
                int4v blo = *(const int4v*)(tb + kc * 2048 + lane * 16);
                int4v bhi = *(const int4v*)(tb + kc * 2048 + 1024 + lane * 16);
                int8v b;
                b[0] = blo[0]; b[1] = blo[1]; b[2] = blo[2]; b[3] = blo[3];
                b[4] = bhi[0]; b[5] = bhi[1]; b[6] = bhi[2]; b[7] = bhi[3];
                acc = __builtin_amdgcn_mfma_scale_f32_16x16x128_f8f6f4(
                          afr[kc], b, acc, 0, 0, 0, SCALE1, 0, SCALE1);
            }
            const float sb = sb_lds[q * (KCODES / NQ) + tl * 16 + col];
#pragma unroll
            for (int r = 0; r < 4; ++r)          // D: col=lane&15, row=hi*4+r
                bs[r] = fmaxf(bs[r], acc[r] + sb);
        }
        // ---- Restage next quarter (2 barriers per transition) ----
        if (q + 1 < NQ) {
            __syncthreads();   // all waves done reading smem
            stage_quarter(bfrag + (size_t)(q + 1) * QBYTES, smem, wave, lane);
            __syncthreads();   // drains vmcnt(0): next quarter resident
        }
    }

    // ---- Per-row max across the 16 col-lanes (masks<16 preserve hi) ----
#pragma unroll
    for (int m = 1; m < 16; m <<= 1)
#pragma unroll
        for (int r = 0; r < 4; ++r)
            bs[r] = fmaxf(bs[r], __shfl_xor(bs[r], m, 64));

    // Lane col==0 of each 16-lane group owns rows {hi*4 + r} of the slab.
    if (col == 0) {
        float s = 0.f;
#pragma unroll
        for (int r = 0; r < 4; ++r) s += bs[r];
        gsum[wave * 4 + hi] = s;
    }
    __syncthreads();
    if (threadIdx.x == 0) {
        float tot = 0.f;
#pragma unroll
        for (int i = 0; i < 4 * WAVES; ++i) tot += gsum[i];
        bpart[blockIdx.x] = tot;
    }
}

// loss = 0.25 * (Sxx - 2*sum_blocks bpart) / (65536*492)
__global__ __launch_bounds__(256) void finalize_k(const float* __restrict__ bpart,
                                                  const float* __restrict__ xsq_part,
                                                  float* __restrict__ out) {
    __shared__ double sm[256];
    int tid = threadIdx.x;
    sm[tid] = (double)bpart[tid];
    __syncthreads();
    for (int st = 128; st > 0; st >>= 1) {
        if (tid < st) sm[tid] += sm[tid + st];
        __syncthreads();
    }
    double S1 = sm[0];
    __syncthreads();
    sm[tid] = (double)xsq_part[tid];
    __syncthreads();
    for (int st = 128; st > 0; st >>= 1) {
        if (tid < st) sm[tid] += sm[tid + st];
        __syncthreads();
    }
    if (tid == 0)
        out[0] = (float)(0.25 * (sm[0] - 2.0 * S1) / ((double)MROWS * (double)DDIM));
}

extern "C" void kernel_launch(void* const* d_in, const int* in_sizes, int n_in,
                              void* d_out, int out_size, void* d_ws, size_t ws_size,
                              hipStream_t stream) {
    const float* x  = (const float*)d_in[0];   // (16,12,4096) f32
    const float* cb = (const float*)d_in[1];   // (1024,492) f32
    float* out = (float*)d_out;

    // workspace layout (~524 KiB)
    char* ws = (char*)d_ws;
    long2v* bfrag   = (long2v*)ws;                                  // 512 KiB
    float* cnorm    = (float*)(ws + (512u << 10));                  // 4 KiB
    float* xsq_part = (float*)(ws + (512u << 10) + 4096);           // 1 KiB
    float* bpart    = (float*)(ws + (512u << 10) + 8192);           // 1 KiB

    prep_bfrag_k<<<128, 256, 0, stream>>>(cb, bfrag);
    prep_cnorm_k<<<KCODES, 64, 0, stream>>>(cb, cnorm);
    xsq_k<<<256, 256, 0, stream>>>(x, xsq_part);
    vq_main_k<<<NBLK, 1024, 0, stream>>>(x, (const unsigned char*)bfrag, cnorm, bpart);
    finalize_k<<<1, 256, 0, stream>>>(bpart, xsq_part, out);
}